// Round 10
// baseline (190.390 us; speedup 1.0000x reference)
//
#include <hip/hip_runtime.h>
#include <cmath>

namespace {
constexpr int BN = 1024;
constexpr int NC = 96;
constexpr int MT = 256;
constexpr int UL = 40;
constexpr int LS = 81;     // 2*UL+1 states
constexpr int PAIRS = 41;  // pairs per row (lane i -> states 2i, 2i+1)

template <int CTRL>
__device__ __forceinline__ float dppf(float v) {
  return __builtin_bit_cast(
      float, __builtin_amdgcn_update_dpp(0, __builtin_bit_cast(int, v), CTRL,
                                         0xf, 0xf, true));
}
__device__ __forceinline__ float rl63(float x) {
  return __builtin_bit_cast(
      float, __builtin_amdgcn_readlane(__builtin_bit_cast(int, x), 63));
}
__device__ __forceinline__ float wave_sum(float x) {
  x += dppf<0x111>(x);
  x += dppf<0x112>(x);
  x += dppf<0x114>(x);
  x += dppf<0x118>(x);
  x += dppf<0x142>(x);
  x += dppf<0x143>(x);
  return rl63(x);
}
// lane i <- lane i-1 (lane 0 <- 0)
__device__ __forceinline__ float wave_shr1(float v) { return dppf<0x138>(v); }
__device__ __forceinline__ float fast_rcp(float x) {
  return __builtin_amdgcn_rcpf(x);
}
__device__ __forceinline__ unsigned packu(float a, float b) {
  unsigned ua = __builtin_bit_cast(unsigned, a) >> 16;
  unsigned ub = __builtin_bit_cast(unsigned, b) & 0xffff0000u;
  return ua | ub;
}
__device__ __forceinline__ float bf_lo(unsigned u) {
  return __builtin_bit_cast(float, u << 16);
}
__device__ __forceinline__ float bf_hi(unsigned u) {
  return __builtin_bit_cast(float, u & 0xffff0000u);
}

constexpr float FQ = 1e8f;       // block-start row scale
constexpr float SEPS = 1e-30f;   // rcp-input floor (NaN-proof)
constexpr float GB = 1099511627776.0f;  // 2^40 mid-block boost (EXACT in fp32)

// One wave per (item, phase). Lane i owns states s=2i, 2i+1.
// 16-step rounds (verified R9) + RAW STORES (R10): rows are stored bf16-
// truncated but UNNORMALIZED, immediately as each step completes (stores
// spread across the round -> acks drain under compute; no clustered burst
// tail of rcp/pack/store). Per-round the 16 raw f32 row sums are stored as
// one coalesced vector (lanes 0..15); combine divides by them. Scale factors
// (FQ start, 2^40 mid-round boost) are carried identically by the stored row
// and its stored sum, so they cancel exactly in combine's division.
// Beta stores row t-1 at step t (its f1 needs step t's pm1); row t0+15 at
// the round end. Layout [b][t][pair], columns reference-aligned as before.
__global__ __launch_bounds__(64) void chain_kernel(
    const float* __restrict__ gout, const int* __restrict__ glabel,
    const int* __restrict__ gw, unsigned* __restrict__ xa,
    unsigned* __restrict__ xb, float* __restrict__ sa,
    float* __restrict__ sb) {
  const int bx = blockIdx.x;
  const int b = bx >> 1, ph = bx & 1;
  const int i = threadIdx.x;
  const float* P = gout + (size_t)b * (NC * MT);  // P[c*MT + t]
  const int* lab = glabel + b * UL;
  const int T = gw[b] >> 2;  // [128,256]

  const int s0 = 2 * i, s1 = s0 + 1;
  const float h0f = (i <= 40) ? 1.f : 0.f;
  const float h1f = (i <= 39) ? 1.f : 0.f;
  const int iw = (i <= 40) ? i : 40;
  const bool act = (i <= 40);

  const float* pB;
  const float* pL;
  float mskf;
  unsigned* outp;  // [b][0][col] in the [b][t][pair] layout
  float* sump;     // per-row raw sums for this chain
  if (ph == 0) {  // alpha
    const int li = (i < UL) ? lab[i] : 0;
    const int lm = (i >= 1 && i < UL) ? lab[i - 1] : 0;
    pB = P;
    pL = P + (size_t)li * MT;
    mskf = (i >= 1 && i <= 39 && li != lm) ? 1.f : 0.f;
    outp = xa + (size_t)b * MT * PAIRS + iw;
    sump = sa + (size_t)b * MT;
  } else {  // beta: class-flipped probs, reversed labels
    const int rli = (i < UL) ? lab[UL - 1 - i] : 0;
    const int rlm = (i >= 1 && i < UL) ? lab[UL - i] : 0;
    pB = P + (size_t)(NC - 1) * MT;
    pL = P + (size_t)(NC - 1 - rli) * MT;
    mskf = (i >= 1 && i <= 39 && rli != rlm) ? 1.f : 0.f;
    outp = xb + (size_t)b * MT * PAIRS + (40 - iw);  // pair-reversed column
    sump = sb + (size_t)b * MT;
  }

  // ---- prob pipeline: current 16-step round unpacked, next in flight ----
  float pbv[16], plv[16];
  float4 LA = *(const float4*)(pB + 0),  LB = *(const float4*)(pB + 4);
  float4 LC = *(const float4*)(pB + 8),  LD = *(const float4*)(pB + 12);
  float4 MA = *(const float4*)(pL + 0),  MB = *(const float4*)(pL + 4);
  float4 MC = *(const float4*)(pL + 8),  MD = *(const float4*)(pL + 12);
  pbv[0] = LA.x;  pbv[1] = LA.y;  pbv[2] = LA.z;  pbv[3] = LA.w;
  pbv[4] = LB.x;  pbv[5] = LB.y;  pbv[6] = LB.z;  pbv[7] = LB.w;
  pbv[8] = LC.x;  pbv[9] = LC.y;  pbv[10] = LC.z; pbv[11] = LC.w;
  pbv[12] = LD.x; pbv[13] = LD.y; pbv[14] = LD.z; pbv[15] = LD.w;
  plv[0] = MA.x;  plv[1] = MA.y;  plv[2] = MA.z;  plv[3] = MA.w;
  plv[4] = MB.x;  plv[5] = MB.y;  plv[6] = MB.z;  plv[7] = MB.w;
  plv[8] = MC.x;  plv[9] = MC.y;  plv[10] = MC.z; plv[11] = MC.w;
  plv[12] = MD.x; plv[13] = MD.y; plv[14] = MD.z; plv[15] = MD.w;
  LA = *(const float4*)(pB + 16); LB = *(const float4*)(pB + 20);
  LC = *(const float4*)(pB + 24); LD = *(const float4*)(pB + 28);
  MA = *(const float4*)(pL + 16); MB = *(const float4*)(pL + 20);
  MC = *(const float4*)(pL + 24); MD = *(const float4*)(pL + 28);

  // ---- t = 0 ----
  float v0 = (i == 0) ? pbv[0] : 0.f;
  float v1 = (i == 0) ? plv[0] : 0.f;

  float sv[16];       // per-lane row totals for this round
  float prev_n0 = 0.f;  // beta: row t-1's n0 (completed at step t)
  if (ph == 0) {
    sv[0] = v0 + v1;  // raw scale matches stored x=1 convention
    if (act) {        // store row 0 immediately (x0=x1=1 at lane 0)
      const float f00 = (i == 0) ? 1.f : 0.f;
      outp[0] = packu(f00, f00);
    }
    v0 *= FQ;
    v1 *= FQ;
  } else {
    v0 *= FQ;
    v1 *= FQ;
    sv[0] = v0 + v1;
    prev_n0 = v0;  // row 0's n0; f1(row0) = pm1 captured at step 1
  }

// Step at time T_, round slot K_. Beta stores row T_-1 (needs this step's
// pm1) for K_>=1; alpha stores row T_ right after computing it. GUARD: 0 in
// unmasked main rounds (bounds known), 1 in tail rounds (runtime t<T checks).
#define CTC_STEP(T_, K_, DOMASK, BOOST, GUARD)                        \
  {                                                                   \
    float pm1 = wave_shr1(v1);                                        \
    if (ph == 1 && (K_) >= 1) {                                       \
      if (act && (!(GUARD) || ((T_)-1) < T))                          \
        outp[((T_)-1) * PAIRS] = packu(prev_n0, pm1);                 \
    }                                                                 \
    if (BOOST) { v0 *= GB; v1 *= GB; pm1 *= GB; }                     \
    float u0 = v0 + pm1;                                              \
    float u1 = (v0 + v1) + pm1 * mskf;                                \
    if (DOMASK) {                                                     \
      const int start_ = LS - 2 * (T - (T_));                         \
      if (s0 < start_) u0 = 0.f;                                      \
      if (s1 < start_) u1 = 0.f;                                      \
    }                                                                 \
    const float x0 = u0 * h0f, x1 = u1 * h1f;                         \
    float n0 = x0 * pbv[(K_)];                                        \
    float n1 = x1 * plv[(K_)];                                        \
    sv[(K_)] = n0 + n1;                                               \
    if (ph == 0) {                                                    \
      if (act && (!(GUARD) || (T_) < T))                              \
        outp[(T_) * PAIRS] = packu(x0, x1);                           \
    }                                                                 \
    v0 = n0; v1 = n1; prev_n0 = n0;                                   \
  }

  // 16 independent wave-sums, breadth-first: 16-way ILP on the DPP trees.
#define WS_LEVEL(CTRL)                                                \
  {                                                                   \
    _Pragma("unroll")                                                 \
    for (int k = 0; k < 16; ++k) sv[k] += dppf<CTRL>(sv[k]);          \
  }

  // Round end: beta's last row store, sum-trees, coalesced sums store,
  // deadbeat rescale. No rcp/pack/store cluster on the row data anymore.
#define CTC_BURST(T0_, GUARD)                                         \
  {                                                                   \
    if (ph == 1) {                                                    \
      float fl = wave_shr1(v1);                                       \
      if (act && (!(GUARD) || ((T0_) + 15) < T))                      \
        outp[((T0_) + 15) * PAIRS] = packu(prev_n0, fl);              \
    }                                                                 \
    WS_LEVEL(0x111) WS_LEVEL(0x112) WS_LEVEL(0x114)                   \
    WS_LEVEL(0x118) WS_LEVEL(0x142) WS_LEVEL(0x143)                   \
    _Pragma("unroll")                                                 \
    for (int k = 0; k < 16; ++k) sv[k] = rl63(sv[k]);                 \
    float ssel = sv[0];                                               \
    _Pragma("unroll")                                                 \
    for (int k = 1; k < 16; ++k) ssel = (i == k) ? sv[k] : ssel;      \
    if (i < 16 && (!(GUARD) || ((T0_) + i) < T))                      \
      sump[(T0_) + i] = ssel;                                         \
    float rb = FQ * fast_rcp(fmaxf(sv[15], SEPS));                    \
    rb = fminf(fmaxf(rb, 1e-20f), 1e20f);                             \
    v0 *= rb; v1 *= rb;                                               \
  }

#define CTC_UNPACK(T0_)                                               \
  {                                                                   \
    pbv[0] = LA.x;  pbv[1] = LA.y;  pbv[2] = LA.z;  pbv[3] = LA.w;    \
    pbv[4] = LB.x;  pbv[5] = LB.y;  pbv[6] = LB.z;  pbv[7] = LB.w;    \
    pbv[8] = LC.x;  pbv[9] = LC.y;  pbv[10] = LC.z; pbv[11] = LC.w;   \
    pbv[12] = LD.x; pbv[13] = LD.y; pbv[14] = LD.z; pbv[15] = LD.w;   \
    plv[0] = MA.x;  plv[1] = MA.y;  plv[2] = MA.z;  plv[3] = MA.w;    \
    plv[4] = MB.x;  plv[5] = MB.y;  plv[6] = MB.z;  plv[7] = MB.w;    \
    plv[8] = MC.x;  plv[9] = MC.y;  plv[10] = MC.z; plv[11] = MC.w;   \
    plv[12] = MD.x; plv[13] = MD.y; plv[14] = MD.z; plv[15] = MD.w;   \
    int np = (T0_) + 16;                                              \
    if (np > 240) np = 240;                                           \
    LA = *(const float4*)(pB + np);      LB = *(const float4*)(pB + np + 4);  \
    LC = *(const float4*)(pB + np + 8);  LD = *(const float4*)(pB + np + 12); \
    MA = *(const float4*)(pL + np);      MB = *(const float4*)(pL + np + 4);  \
    MC = *(const float4*)(pL + np + 8);  MD = *(const float4*)(pL + np + 12); \
  }

  // ---- prologue: steps 1..15, rows 0..15 (T>=128 -> unmasked) ----
#pragma unroll
  for (int k = 1; k < 8; ++k) CTC_STEP(k, k, false, 0, 0);
  CTC_STEP(8, 8, false, 1, 0);
#pragma unroll
  for (int k = 9; k < 16; ++k) CTC_STEP(k, k, false, 0, 0);
  CTC_BURST(0, 0);

  // ---- main: unmasked fast path (t0+15 <= T-41) ----
  int t0 = 16;
  for (; t0 + 56 <= T; t0 += 16) {
    CTC_UNPACK(t0);
#pragma unroll
    for (int k = 0; k < 8; ++k) CTC_STEP(t0 + k, k, false, k == 8 ? 1 : 0, 0);
    CTC_STEP(t0 + 8, 8, false, 1, 0);
#pragma unroll
    for (int k = 9; k < 16; ++k) CTC_STEP(t0 + k, k, false, 0, 0);
    CTC_BURST(t0, 0);
  }
  // ---- tail: masked rounds with runtime store guards ----
  for (; t0 < T; t0 += 16) {
    CTC_UNPACK(t0);
#pragma unroll
    for (int k = 0; k < 8; ++k) CTC_STEP(t0 + k, k, true, 0, 1);
    CTC_STEP(t0 + 8, 8, true, 1, 1);
#pragma unroll
    for (int k = 9; k < 16; ++k) CTC_STEP(t0 + k, k, true, 0, 1);
    CTC_BURST(t0, 1);
  }
#undef CTC_STEP
#undef CTC_BURST
#undef CTC_UNPACK
#undef WS_LEVEL
}

// Fully parallel combine: block = item, thread = t. Rows are raw; normalize
// per element by invA/invB (per-factor, overflow-safe: each normalized value
// <= ~1). lh_t = sum_p (x[t][p]/sA[t]) * (b[T-1-t][p]/sB[T-1-t]).
__global__ __launch_bounds__(256) void combine_kernel(
    const int* __restrict__ gw, const unsigned* __restrict__ xa,
    const unsigned* __restrict__ xb, const float* __restrict__ sa,
    const float* __restrict__ sb, float* __restrict__ loss_out) {
  const int b = blockIdx.x;
  const int tid = threadIdx.x;
  const int T = gw[b] >> 2;
  float lsum = 0.f;
  if (tid < T) {
    const unsigned* A = xa + ((size_t)b * MT + tid) * PAIRS;
    const unsigned* Bb = xb + ((size_t)b * MT + (T - 1 - tid)) * PAIRS;
    const float invA = fast_rcp(fmaxf(sa[(size_t)b * MT + tid], SEPS));
    const float invB =
        fast_rcp(fmaxf(sb[(size_t)b * MT + (T - 1 - tid)], SEPS));
    float d = 0.f;
#pragma unroll
    for (int p = 0; p < PAIRS; ++p) {
      const unsigned av = A[p];
      const unsigned bv = Bb[p];
      d = fmaf(bf_lo(av) * invA, bf_lo(bv) * invB, d);
      d = fmaf(bf_hi(av) * invA, bf_hi(bv) * invB, d);
    }
    lsum = -__logf(fmaxf(d, 1e-37f));
  }
  lsum = wave_sum(lsum);
  __shared__ float part[4];
  if ((tid & 63) == 0) part[tid >> 6] = lsum;
  __syncthreads();
  if (tid == 0) {
    float L = part[0] + part[1] + part[2] + part[3];
    loss_out[b] = fminf(fmaxf(L, -1e30f), 1e30f);  // fmin/fmax absorb NaN
  }
}

__global__ void reduce_kernel(const float* __restrict__ loss_in,
                              float* __restrict__ out) {
  __shared__ double sm[256];
  const int tid = threadIdx.x;
  double s = 0.0;
  for (int k = tid; k < BN; k += 256) s += (double)loss_in[k];
  sm[tid] = s;
  __syncthreads();
  for (int w = 128; w >= 1; w >>= 1) {
    if (tid < w) sm[tid] += sm[tid + w];
    __syncthreads();
  }
  if (tid == 0) out[0] = (float)sm[0];
}
}  // namespace

extern "C" void kernel_launch(void* const* d_in, const int* in_sizes, int n_in,
                              void* d_out, int out_size, void* d_ws, size_t ws_size,
                              hipStream_t stream) {
  const float* gout = (const float*)d_in[0];
  const int* glabel = (const int*)d_in[1];
  const int* gw = (const int*)d_in[2];
  unsigned* xa = (unsigned*)d_ws;                  // BN*MT*PAIRS uints (43 MB)
  unsigned* xb = xa + (size_t)BN * MT * PAIRS;     // 43 MB
  float* sa = (float*)(xb + (size_t)BN * MT * PAIRS);  // BN*MT f32 (1 MB)
  float* sb = sa + (size_t)BN * MT;                    // 1 MB
  float* loss = sb + (size_t)BN * MT;                  // 4 KB
  chain_kernel<<<2 * BN, 64, 0, stream>>>(gout, glabel, gw, xa, xb, sa, sb);
  combine_kernel<<<BN, 256, 0, stream>>>(gw, xa, xb, sa, sb, loss);
  reduce_kernel<<<1, 256, 0, stream>>>(loss, (float*)d_out);
}

// Round 11
// 184.650 us; speedup vs baseline: 1.0311x; 1.0311x over previous
//
#include <hip/hip_runtime.h>
#include <cmath>

namespace {
constexpr int BN = 1024;
constexpr int NC = 96;
constexpr int MT = 256;
constexpr int UL = 40;
constexpr int LS = 81;     // 2*UL+1 states
constexpr int PAIRS = 41;  // pairs per row (lane i -> states 2i, 2i+1)

template <int CTRL>
__device__ __forceinline__ float dppf(float v) {
  return __builtin_bit_cast(
      float, __builtin_amdgcn_update_dpp(0, __builtin_bit_cast(int, v), CTRL,
                                         0xf, 0xf, true));
}
__device__ __forceinline__ float rl63(float x) {
  return __builtin_bit_cast(
      float, __builtin_amdgcn_readlane(__builtin_bit_cast(int, x), 63));
}
__device__ __forceinline__ float wave_sum(float x) {
  x += dppf<0x111>(x);
  x += dppf<0x112>(x);
  x += dppf<0x114>(x);
  x += dppf<0x118>(x);
  x += dppf<0x142>(x);
  x += dppf<0x143>(x);
  return rl63(x);
}
// lane i <- lane i-1 (lane 0 <- 0)
__device__ __forceinline__ float wave_shr1(float v) { return dppf<0x138>(v); }
__device__ __forceinline__ float fast_rcp(float x) {
  return __builtin_amdgcn_rcpf(x);
}
__device__ __forceinline__ unsigned packu(float a, float b) {
  unsigned ua = __builtin_bit_cast(unsigned, a) >> 16;
  unsigned ub = __builtin_bit_cast(unsigned, b) & 0xffff0000u;
  return ua | ub;
}
__device__ __forceinline__ float bf_lo(unsigned u) {
  return __builtin_bit_cast(float, u << 16);
}
__device__ __forceinline__ float bf_hi(unsigned u) {
  return __builtin_bit_cast(float, u & 0xffff0000u);
}

constexpr float FQ = 1e8f;       // block-start row scale
constexpr float SEPS = 1e-30f;   // rcp-input floor (NaN-proof)
constexpr float GB = 1099511627776.0f;  // 2^40 mid-round boost (EXACT in fp32)

// One wave per (item, phase). Lane i owns states s=2i, 2i+1.
// 16-step rounds + coalesced [b][t][pair] stores (verified R9, 183.3us).
// R11: CROSS-ROUND BURST PIPELINE. Round state is double-buffered (A/B).
// At round end only the deadbeat rescale runs (single 6-op DPP tree on
// sv[15] — bit-identical value to R9's). The full burst (16 sum-trees,
// readlanes, packs, row stores) of round n is DEFERRED into round n+1's
// scheduling region: its latency chains interleave with the new round's
// step chain instead of serializing after it. Tail rounds keep the
// immediate burst. All math bit-identical to R9.
__global__ __launch_bounds__(64) void chain_kernel(
    const float* __restrict__ gout, const int* __restrict__ glabel,
    const int* __restrict__ gw, unsigned* __restrict__ xa,
    unsigned* __restrict__ xb) {
  const int bx = blockIdx.x;
  const int b = bx >> 1, ph = bx & 1;
  const int i = threadIdx.x;
  const float* P = gout + (size_t)b * (NC * MT);  // P[c*MT + t]
  const int* lab = glabel + b * UL;
  const int T = gw[b] >> 2;  // [128,256]

  const int s0 = 2 * i, s1 = s0 + 1;
  const float h0f = (i <= 40) ? 1.f : 0.f;
  const float h1f = (i <= 39) ? 1.f : 0.f;
  const int iw = (i <= 40) ? i : 40;
  const bool act = (i <= 40);

  const float* pB;
  const float* pL;
  float mskf;
  unsigned* outp;  // [b][0][col] in the [b][t][pair] layout
  if (ph == 0) {  // alpha
    const int li = (i < UL) ? lab[i] : 0;
    const int lm = (i >= 1 && i < UL) ? lab[i - 1] : 0;
    pB = P;
    pL = P + (size_t)li * MT;
    mskf = (i >= 1 && i <= 39 && li != lm) ? 1.f : 0.f;
    outp = xa + (size_t)b * MT * PAIRS + iw;
  } else {  // beta: class-flipped probs, reversed labels
    const int rli = (i < UL) ? lab[UL - 1 - i] : 0;
    const int rlm = (i >= 1 && i < UL) ? lab[UL - i] : 0;
    pB = P + (size_t)(NC - 1) * MT;
    pL = P + (size_t)(NC - 1 - rli) * MT;
    mskf = (i >= 1 && i <= 39 && rli != rlm) ? 1.f : 0.f;
    outp = xb + (size_t)b * MT * PAIRS + (40 - iw);  // pair-reversed column
  }

  // ---- prob pipeline: current 16-step round unpacked, next in flight ----
  float pbv[16], plv[16];
  float4 LA = *(const float4*)(pB + 0),  LB = *(const float4*)(pB + 4);
  float4 LC = *(const float4*)(pB + 8),  LD = *(const float4*)(pB + 12);
  float4 MA = *(const float4*)(pL + 0),  MB = *(const float4*)(pL + 4);
  float4 MC = *(const float4*)(pL + 8),  MD = *(const float4*)(pL + 12);
  pbv[0] = LA.x;  pbv[1] = LA.y;  pbv[2] = LA.z;  pbv[3] = LA.w;
  pbv[4] = LB.x;  pbv[5] = LB.y;  pbv[6] = LB.z;  pbv[7] = LB.w;
  pbv[8] = LC.x;  pbv[9] = LC.y;  pbv[10] = LC.z; pbv[11] = LC.w;
  pbv[12] = LD.x; pbv[13] = LD.y; pbv[14] = LD.z; pbv[15] = LD.w;
  plv[0] = MA.x;  plv[1] = MA.y;  plv[2] = MA.z;  plv[3] = MA.w;
  plv[4] = MB.x;  plv[5] = MB.y;  plv[6] = MB.z;  plv[7] = MB.w;
  plv[8] = MC.x;  plv[9] = MC.y;  plv[10] = MC.z; plv[11] = MC.w;
  plv[12] = MD.x; plv[13] = MD.y; plv[14] = MD.z; plv[15] = MD.w;
  LA = *(const float4*)(pB + 16); LB = *(const float4*)(pB + 20);
  LC = *(const float4*)(pB + 24); LD = *(const float4*)(pB + 28);
  MA = *(const float4*)(pL + 16); MB = *(const float4*)(pL + 20);
  MC = *(const float4*)(pL + 24); MD = *(const float4*)(pL + 28);

  // ---- t = 0 ----
  float v0 = (i == 0) ? pbv[0] : 0.f;
  float v1 = (i == 0) ? plv[0] : 0.f;

  // Double-buffered round state (A/B): rows + per-lane row totals.
  float f0A[16], f1A[16], svA[16];
  float f0B[16], f1B[16], svB[16];
  if (ph == 0) {
    svA[0] = v0 + v1;               // raw scale matches x=1 convention
    f0A[0] = (i == 0) ? 1.f : 0.f;  // x = a_raw/p at t=0
    f1A[0] = f0A[0];
    v0 *= FQ;
    v1 *= FQ;
  } else {
    v0 *= FQ;
    v1 *= FQ;
    svA[0] = v0 + v1;
    f0A[0] = v0;
    f1A[0] = 0.f;  // overwritten by step k=1's pm1 (same scale)
  }

// Step at time T_, round slot K_, state-buffer suffix S.
#define CTC_STEP(S, T_, K_, DOMASK, BOOST)                            \
  {                                                                   \
    float pm1 = wave_shr1(v1);                                        \
    if (ph == 1 && (K_) >= 1) f1##S[(K_)-1] = pm1;                    \
    if (BOOST) { v0 *= GB; v1 *= GB; pm1 *= GB; }                     \
    float u0 = v0 + pm1;                                              \
    float u1 = (v0 + v1) + pm1 * mskf;                                \
    if (DOMASK) {                                                     \
      const int start_ = LS - 2 * (T - (T_));                         \
      if (s0 < start_) u0 = 0.f;                                      \
      if (s1 < start_) u1 = 0.f;                                      \
    }                                                                 \
    const float x0 = u0 * h0f, x1 = u1 * h1f;                         \
    float n0 = x0 * pbv[(K_)];                                        \
    float n1 = x1 * plv[(K_)];                                        \
    sv##S[(K_)] = n0 + n1;                                            \
    v0 = n0; v1 = n1;                                                 \
    if (ph == 0) { f0##S[(K_)] = x0; f1##S[(K_)] = x1; }              \
    else { f0##S[(K_)] = n0; }                                        \
  }

  // Round end: capture beta's last f1, then CHEAP deadbeat rescale via a
  // single 6-op DPP tree on a COPY of sv[15] (sv[15] itself left intact for
  // the deferred burst). Bit-identical rb to R9.
#define CTC_ROUNDEND(S)                                               \
  {                                                                   \
    if (ph == 1) f1##S[15] = wave_shr1(v1);                           \
    float w_ = sv##S[15];                                             \
    w_ += dppf<0x111>(w_); w_ += dppf<0x112>(w_);                     \
    w_ += dppf<0x114>(w_); w_ += dppf<0x118>(w_);                     \
    w_ += dppf<0x142>(w_); w_ += dppf<0x143>(w_);                     \
    float rb = FQ * fast_rcp(fmaxf(rl63(w_), SEPS));                  \
    rb = fminf(fmaxf(rb, 1e-20f), 1e20f);                             \
    v0 *= rb; v1 *= rb;                                               \
  }

  // 16 independent wave-sums, breadth-first, on buffer S.
#define WS_LEVEL(S, CTRL)                                             \
  {                                                                   \
    _Pragma("unroll")                                                 \
    for (int k = 0; k < 16; ++k) sv##S[k] += dppf<CTRL>(sv##S[k]);    \
  }

  // Deferred burst of a FINISHED round (buffer S, rows T0_..T0_+15, all
  // < T guaranteed for main rounds): trees, readlanes, packs, stores.
  // Independent of the live recurrence -> scheduler interleaves freely.
#define CTC_DEFBURST(S, T0_)                                          \
  {                                                                   \
    WS_LEVEL(S, 0x111) WS_LEVEL(S, 0x112) WS_LEVEL(S, 0x114)          \
    WS_LEVEL(S, 0x118) WS_LEVEL(S, 0x142) WS_LEVEL(S, 0x143)          \
    _Pragma("unroll")                                                 \
    for (int k = 0; k < 16; ++k) sv##S[k] = rl63(sv##S[k]);           \
    if (act) {                                                        \
      unsigned ob[16];                                                \
      _Pragma("unroll")                                               \
      for (int k = 0; k < 16; ++k) {                                  \
        float inv = fast_rcp(fmaxf(sv##S[k], SEPS));                  \
        ob[k] = packu(f0##S[k] * inv, f1##S[k] * inv);                \
      }                                                               \
      _Pragma("unroll")                                               \
      for (int k = 0; k < 16; ++k)                                    \
        outp[((T0_) + k) * PAIRS] = ob[k];  /* wave-coalesced */      \
    }                                                                 \
  }

  // Immediate masked-tail burst (R9 semantics, runtime guards).
#define CTC_TAILBURST(S, T0_)                                         \
  {                                                                   \
    if (ph == 1) f1##S[15] = wave_shr1(v1); /* before rescale! */     \
    WS_LEVEL(S, 0x111) WS_LEVEL(S, 0x112) WS_LEVEL(S, 0x114)          \
    WS_LEVEL(S, 0x118) WS_LEVEL(S, 0x142) WS_LEVEL(S, 0x143)          \
    _Pragma("unroll")                                                 \
    for (int k = 0; k < 16; ++k) sv##S[k] = rl63(sv##S[k]);           \
    if (act) {                                                        \
      unsigned ob[16];                                                \
      _Pragma("unroll")                                               \
      for (int k = 0; k < 16; ++k) {                                  \
        float inv = fast_rcp(fmaxf(sv##S[k], SEPS));                  \
        ob[k] = packu(f0##S[k] * inv, f1##S[k] * inv);                \
      }                                                               \
      _Pragma("unroll")                                               \
      for (int k = 0; k < 16; ++k)                                    \
        if ((T0_) + k < T) outp[((T0_) + k) * PAIRS] = ob[k];         \
    }                                                                 \
    float rb = FQ * fast_rcp(fmaxf(sv##S[15], SEPS));                 \
    rb = fminf(fmaxf(rb, 1e-20f), 1e20f);                             \
    v0 *= rb; v1 *= rb;                                               \
  }

#define CTC_UNPACK(T0_)                                               \
  {                                                                   \
    pbv[0] = LA.x;  pbv[1] = LA.y;  pbv[2] = LA.z;  pbv[3] = LA.w;    \
    pbv[4] = LB.x;  pbv[5] = LB.y;  pbv[6] = LB.z;  pbv[7] = LB.w;    \
    pbv[8] = LC.x;  pbv[9] = LC.y;  pbv[10] = LC.z; pbv[11] = LC.w;   \
    pbv[12] = LD.x; pbv[13] = LD.y; pbv[14] = LD.z; pbv[15] = LD.w;   \
    plv[0] = MA.x;  plv[1] = MA.y;  plv[2] = MA.z;  plv[3] = MA.w;    \
    plv[4] = MB.x;  plv[5] = MB.y;  plv[6] = MB.z;  plv[7] = MB.w;    \
    plv[8] = MC.x;  plv[9] = MC.y;  plv[10] = MC.z; plv[11] = MC.w;   \
    plv[12] = MD.x; plv[13] = MD.y; plv[14] = MD.z; plv[15] = MD.w;   \
    int np = (T0_) + 16;                                              \
    if (np > 240) np = 240;                                           \
    LA = *(const float4*)(pB + np);      LB = *(const float4*)(pB + np + 4);  \
    LC = *(const float4*)(pB + np + 8);  LD = *(const float4*)(pB + np + 12); \
    MA = *(const float4*)(pL + np);      MB = *(const float4*)(pL + np + 4);  \
    MC = *(const float4*)(pL + np + 8);  MD = *(const float4*)(pL + np + 12); \
  }

#define CTC_ROUND(S, T0_)                                             \
  {                                                                   \
    CTC_UNPACK(T0_);                                                  \
    _Pragma("unroll")                                                 \
    for (int k = 0; k < 8; ++k) CTC_STEP(S, (T0_) + k, k, false, 0);  \
    CTC_STEP(S, (T0_) + 8, 8, false, 1);                              \
    _Pragma("unroll")                                                 \
    for (int k = 9; k < 16; ++k) CTC_STEP(S, (T0_) + k, k, false, 0); \
    CTC_ROUNDEND(S);                                                  \
  }

  // ---- prologue round 0: steps 1..15 into A (T>=128 -> unmasked) ----
#pragma unroll
  for (int k = 1; k < 8; ++k) CTC_STEP(A, k, k, false, 0);
  CTC_STEP(A, 8, 8, false, 1);
#pragma unroll
  for (int k = 9; k < 16; ++k) CTC_STEP(A, k, k, false, 0);
  CTC_ROUNDEND(A);
  // pending burst: A @ rows 0..15

  // ---- main: pairs of unmasked rounds, burst pipelined one round back ----
  int t0 = 16;
  for (; t0 + 72 <= T; t0 += 32) {
    CTC_ROUND(B, t0);
    CTC_DEFBURST(A, t0 - 16);
    CTC_ROUND(A, t0 + 16);
    CTC_DEFBURST(B, t0);
  }
  // ---- optional single leftover main round ----
  if (t0 + 56 <= T) {
    CTC_ROUND(B, t0);
    CTC_DEFBURST(A, t0 - 16);
    CTC_DEFBURST(B, t0);  // flush
    t0 += 16;
  } else {
    CTC_DEFBURST(A, t0 - 16);  // flush
  }
  // ---- tail: masked rounds, immediate burst (buffer A) ----
  for (; t0 < T; t0 += 16) {
    CTC_UNPACK(t0);
#pragma unroll
    for (int k = 0; k < 8; ++k) CTC_STEP(A, t0 + k, k, true, 0);
    CTC_STEP(A, t0 + 8, 8, true, 1);
#pragma unroll
    for (int k = 9; k < 16; ++k) CTC_STEP(A, t0 + k, k, true, 0);
    CTC_TAILBURST(A, t0);
  }
#undef CTC_STEP
#undef CTC_ROUNDEND
#undef CTC_DEFBURST
#undef CTC_TAILBURST
#undef CTC_UNPACK
#undef CTC_ROUND
#undef WS_LEVEL
}

// Fully parallel combine: block = item, thread = t. With the [b][t][pair]
// layout each thread's two rows are CONTIGUOUS 41-dword runs; adjacent
// threads read adjacent rows -> wave-level streams coalesce. lh_t =
// sum_p x'[t][p] * b'[T-1-t][p]; rows pre-normalized at store.
__global__ __launch_bounds__(256) void combine_kernel(
    const int* __restrict__ gw, const unsigned* __restrict__ xa,
    const unsigned* __restrict__ xb, float* __restrict__ loss_out) {
  const int b = blockIdx.x;
  const int tid = threadIdx.x;
  const int T = gw[b] >> 2;
  float lsum = 0.f;
  if (tid < T) {
    const unsigned* A = xa + ((size_t)b * MT + tid) * PAIRS;
    const unsigned* Bb = xb + ((size_t)b * MT + (T - 1 - tid)) * PAIRS;
    float d = 0.f;
#pragma unroll
    for (int p = 0; p < PAIRS; ++p) {
      const unsigned av = A[p];
      const unsigned bv = Bb[p];
      d = fmaf(bf_lo(av), bf_lo(bv), d);
      d = fmaf(bf_hi(av), bf_hi(bv), d);
    }
    lsum = -__logf(fmaxf(d, 1e-37f));
  }
  lsum = wave_sum(lsum);
  __shared__ float part[4];
  if ((tid & 63) == 0) part[tid >> 6] = lsum;
  __syncthreads();
  if (tid == 0) {
    float L = part[0] + part[1] + part[2] + part[3];
    loss_out[b] = fminf(fmaxf(L, -1e30f), 1e30f);  // fmin/fmax absorb NaN
  }
}

__global__ void reduce_kernel(const float* __restrict__ loss_in,
                              float* __restrict__ out) {
  __shared__ double sm[256];
  const int tid = threadIdx.x;
  double s = 0.0;
  for (int k = tid; k < BN; k += 256) s += (double)loss_in[k];
  sm[tid] = s;
  __syncthreads();
  for (int w = 128; w >= 1; w >>= 1) {
    if (tid < w) sm[tid] += sm[tid + w];
    __syncthreads();
  }
  if (tid == 0) out[0] = (float)sm[0];
}
}  // namespace

extern "C" void kernel_launch(void* const* d_in, const int* in_sizes, int n_in,
                              void* d_out, int out_size, void* d_ws, size_t ws_size,
                              hipStream_t stream) {
  const float* gout = (const float*)d_in[0];
  const int* glabel = (const int*)d_in[1];
  const int* gw = (const int*)d_in[2];
  unsigned* xa = (unsigned*)d_ws;                  // BN*MT*PAIRS uints (43 MB)
  unsigned* xb = xa + (size_t)BN * MT * PAIRS;     // 43 MB
  float* loss = (float*)(xb + (size_t)BN * MT * PAIRS);  // 4 KB
  chain_kernel<<<2 * BN, 64, 0, stream>>>(gout, glabel, gw, xa, xb);
  combine_kernel<<<BN, 256, 0, stream>>>(gw, xa, xb, loss);
  reduce_kernel<<<1, 256, 0, stream>>>(loss, (float*)d_out);
}

// Round 12
// 184.389 us; speedup vs baseline: 1.0325x; 1.0014x over previous
//
#include <hip/hip_runtime.h>
#include <cmath>

namespace {
constexpr int BN = 1024;
constexpr int NC = 96;
constexpr int MT = 256;
constexpr int UL = 40;
constexpr int LS = 81;     // 2*UL+1 states
constexpr int PAIRS = 41;  // pairs per row (lane i -> states 2i, 2i+1)

template <int CTRL>
__device__ __forceinline__ float dppf(float v) {
  return __builtin_bit_cast(
      float, __builtin_amdgcn_update_dpp(0, __builtin_bit_cast(int, v), CTRL,
                                         0xf, 0xf, true));
}
__device__ __forceinline__ float rl63(float x) {
  return __builtin_bit_cast(
      float, __builtin_amdgcn_readlane(__builtin_bit_cast(int, x), 63));
}
__device__ __forceinline__ float wave_sum(float x) {
  x += dppf<0x111>(x);
  x += dppf<0x112>(x);
  x += dppf<0x114>(x);
  x += dppf<0x118>(x);
  x += dppf<0x142>(x);
  x += dppf<0x143>(x);
  return rl63(x);
}
// lane i <- lane i-1 (lane 0 <- 0)
__device__ __forceinline__ float wave_shr1(float v) { return dppf<0x138>(v); }
__device__ __forceinline__ float fast_rcp(float x) {
  return __builtin_amdgcn_rcpf(x);
}
__device__ __forceinline__ unsigned packu(float a, float b) {
  unsigned ua = __builtin_bit_cast(unsigned, a) >> 16;
  unsigned ub = __builtin_bit_cast(unsigned, b) & 0xffff0000u;
  return ua | ub;
}
__device__ __forceinline__ float bf_lo(unsigned u) {
  return __builtin_bit_cast(float, u << 16);
}
__device__ __forceinline__ float bf_hi(unsigned u) {
  return __builtin_bit_cast(float, u & 0xffff0000u);
}

constexpr float FQ = 1e8f;       // block-start row scale
constexpr float SEPS = 1e-30f;   // rcp-input floor (NaN-proof)
constexpr float GB = 1099511627776.0f;  // 2^40 mid-block boost (EXACT in fp32)

// One wave per (item, phase). Lane i owns states s=2i, 2i+1.
// DEFERRED-SUM scheme (verified round 3) + COALESCED [b][t][pair] stores
// (verified round 7). 16-STEP ROUNDS (verified round 9, best=183.3us):
// depth-1 prefetch, but each round's compute covers the 64-line pL-gather
// latency and the number of latency exposures is halved (32 -> 16 at
// T=256). Mid-round numerical guard: after step 8's pm1 capture, v is
// boosted by G=2^40 (exact power-of-2, zero rounding); rows >= 8 carry G
// uniformly, each row is normalized by its OWN raw sum at pack time (G
// cancels), block-end deadbeat rb = FQ/sv[15] absorbs it.
__global__ __launch_bounds__(64) void chain_kernel(
    const float* __restrict__ gout, const int* __restrict__ glabel,
    const int* __restrict__ gw, unsigned* __restrict__ xa,
    unsigned* __restrict__ xb) {
  const int bx = blockIdx.x;
  const int b = bx >> 1, ph = bx & 1;
  const int i = threadIdx.x;
  const float* P = gout + (size_t)b * (NC * MT);  // P[c*MT + t]
  const int* lab = glabel + b * UL;
  const int T = gw[b] >> 2;  // [128,256]

  const int s0 = 2 * i, s1 = s0 + 1;
  const float h0f = (i <= 40) ? 1.f : 0.f;
  const float h1f = (i <= 39) ? 1.f : 0.f;
  const int iw = (i <= 40) ? i : 40;
  const bool act = (i <= 40);

  const float* pB;
  const float* pL;
  float mskf;
  unsigned* outp;  // points at [b][0][col] in the [b][t][pair] layout
  if (ph == 0) {  // alpha
    const int li = (i < UL) ? lab[i] : 0;
    const int lm = (i >= 1 && i < UL) ? lab[i - 1] : 0;
    pB = P;
    pL = P + (size_t)li * MT;
    mskf = (i >= 1 && i <= 39 && li != lm) ? 1.f : 0.f;
    outp = xa + (size_t)b * MT * PAIRS + iw;
  } else {  // beta: class-flipped probs, reversed labels
    const int rli = (i < UL) ? lab[UL - 1 - i] : 0;
    const int rlm = (i >= 1 && i < UL) ? lab[UL - i] : 0;
    pB = P + (size_t)(NC - 1) * MT;
    pL = P + (size_t)(NC - 1 - rli) * MT;
    mskf = (i >= 1 && i <= 39 && rli != rlm) ? 1.f : 0.f;
    outp = xb + (size_t)b * MT * PAIRS + (40 - iw);  // pair-reversed column
  }

  // ---- prob pipeline: current 16-step block unpacked, next in flight ----
  float pbv[16], plv[16];
  float4 LA = *(const float4*)(pB + 0),  LB = *(const float4*)(pB + 4);
  float4 LC = *(const float4*)(pB + 8),  LD = *(const float4*)(pB + 12);
  float4 MA = *(const float4*)(pL + 0),  MB = *(const float4*)(pL + 4);
  float4 MC = *(const float4*)(pL + 8),  MD = *(const float4*)(pL + 12);
  pbv[0] = LA.x;  pbv[1] = LA.y;  pbv[2] = LA.z;  pbv[3] = LA.w;
  pbv[4] = LB.x;  pbv[5] = LB.y;  pbv[6] = LB.z;  pbv[7] = LB.w;
  pbv[8] = LC.x;  pbv[9] = LC.y;  pbv[10] = LC.z; pbv[11] = LC.w;
  pbv[12] = LD.x; pbv[13] = LD.y; pbv[14] = LD.z; pbv[15] = LD.w;
  plv[0] = MA.x;  plv[1] = MA.y;  plv[2] = MA.z;  plv[3] = MA.w;
  plv[4] = MB.x;  plv[5] = MB.y;  plv[6] = MB.z;  plv[7] = MB.w;
  plv[8] = MC.x;  plv[9] = MC.y;  plv[10] = MC.z; plv[11] = MC.w;
  plv[12] = MD.x; plv[13] = MD.y; plv[14] = MD.z; plv[15] = MD.w;
  LA = *(const float4*)(pB + 16); LB = *(const float4*)(pB + 20);
  LC = *(const float4*)(pB + 24); LD = *(const float4*)(pB + 28);
  MA = *(const float4*)(pL + 16); MB = *(const float4*)(pL + 20);
  MC = *(const float4*)(pL + 24); MD = *(const float4*)(pL + 28);

  // ---- t = 0 ----
  float v0 = (i == 0) ? pbv[0] : 0.f;
  float v1 = (i == 0) ? plv[0] : 0.f;

  float f0[16], f1[16], sv[16];  // 16-step row buffer + per-lane row totals
  if (ph == 0) {
    sv[0] = v0 + v1;               // raw scale matches x=1 convention
    f0[0] = (i == 0) ? 1.f : 0.f;  // x = a_raw/p at t=0
    f1[0] = f0[0];
    v0 *= FQ;
    v1 *= FQ;
  } else {
    v0 *= FQ;
    v1 *= FQ;
    sv[0] = v0 + v1;
    f0[0] = v0;
    f1[0] = 0.f;  // overwritten by step k=1's pm1 (same scale)
  }

// BOOST: 1 at k==8 (v,pm1 scaled by 2^40 AFTER pm1 capture so row 7's beta
// f1 slot stays at row-7 scale), else 0.
#define CTC_STEP(T_, K_, DOMASK, BOOST)                               \
  {                                                                   \
    float pm1 = wave_shr1(v1);                                        \
    if (ph == 1 && (K_) >= 1) f1[(K_)-1] = pm1;                       \
    if (BOOST) { v0 *= GB; v1 *= GB; pm1 *= GB; }                     \
    float u0 = v0 + pm1;                                              \
    float u1 = (v0 + v1) + pm1 * mskf;                                \
    if (DOMASK) {                                                     \
      const int start_ = LS - 2 * (T - (T_));                         \
      if (s0 < start_) u0 = 0.f;                                      \
      if (s1 < start_) u1 = 0.f;                                      \
    }                                                                 \
    const float x0 = u0 * h0f, x1 = u1 * h1f;                         \
    float n0 = x0 * pbv[(K_)];                                        \
    float n1 = x1 * plv[(K_)];                                        \
    sv[(K_)] = n0 + n1;                                               \
    v0 = n0; v1 = n1;                                                 \
    if (ph == 0) { f0[(K_)] = x0; f1[(K_)] = x1; }                    \
    else { f0[(K_)] = n0; }                                           \
  }

  // 16 independent wave-sums, breadth-first: 16-way ILP on the DPP trees.
#define WS_LEVEL(CTRL)                                                \
  {                                                                   \
    _Pragma("unroll")                                                 \
    for (int k = 0; k < 16; ++k) sv[k] += dppf<CTRL>(sv[k]);          \
  }

#define CTC_BURST(T0_)                                                \
  {                                                                   \
    if (ph == 1) f1[15] = wave_shr1(v1); /* before rescale! */        \
    WS_LEVEL(0x111) WS_LEVEL(0x112) WS_LEVEL(0x114)                   \
    WS_LEVEL(0x118) WS_LEVEL(0x142) WS_LEVEL(0x143)                   \
    _Pragma("unroll")                                                 \
    for (int k = 0; k < 16; ++k) sv[k] = rl63(sv[k]);                 \
    if (act) {                                                        \
      unsigned ob[16];                                                \
      _Pragma("unroll")                                               \
      for (int k = 0; k < 16; ++k) {                                  \
        float inv = fast_rcp(fmaxf(sv[k], SEPS));                     \
        ob[k] = packu(f0[k] * inv, f1[k] * inv);                      \
      }                                                               \
      if ((T0_) + 15 < T) {                                           \
        _Pragma("unroll")                                             \
        for (int k = 0; k < 16; ++k)                                  \
          outp[((T0_) + k) * PAIRS] = ob[k];  /* wave-coalesced */    \
      } else {                                                        \
        _Pragma("unroll")                                             \
        for (int k = 0; k < 16; ++k)                                  \
          if ((T0_) + k < T) outp[((T0_) + k) * PAIRS] = ob[k];       \
      }                                                               \
    }                                                                 \
    float rb = FQ * fast_rcp(fmaxf(sv[15], SEPS));                    \
    rb = fminf(fmaxf(rb, 1e-20f), 1e20f);                             \
    v0 *= rb; v1 *= rb;                                               \
  }

#define CTC_UNPACK(T0_)                                               \
  {                                                                   \
    pbv[0] = LA.x;  pbv[1] = LA.y;  pbv[2] = LA.z;  pbv[3] = LA.w;    \
    pbv[4] = LB.x;  pbv[5] = LB.y;  pbv[6] = LB.z;  pbv[7] = LB.w;    \
    pbv[8] = LC.x;  pbv[9] = LC.y;  pbv[10] = LC.z; pbv[11] = LC.w;   \
    pbv[12] = LD.x; pbv[13] = LD.y; pbv[14] = LD.z; pbv[15] = LD.w;   \
    plv[0] = MA.x;  plv[1] = MA.y;  plv[2] = MA.z;  plv[3] = MA.w;    \
    plv[4] = MB.x;  plv[5] = MB.y;  plv[6] = MB.z;  plv[7] = MB.w;    \
    plv[8] = MC.x;  plv[9] = MC.y;  plv[10] = MC.z; plv[11] = MC.w;   \
    plv[12] = MD.x; plv[13] = MD.y; plv[14] = MD.z; plv[15] = MD.w;   \
    int np = (T0_) + 16;                                              \
    if (np > 240) np = 240;                                           \
    LA = *(const float4*)(pB + np);      LB = *(const float4*)(pB + np + 4);  \
    LC = *(const float4*)(pB + np + 8);  LD = *(const float4*)(pB + np + 12); \
    MA = *(const float4*)(pL + np);      MB = *(const float4*)(pL + np + 4);  \
    MC = *(const float4*)(pL + np + 8);  MD = *(const float4*)(pL + np + 12); \
  }

  // ---- prologue: steps 1..15, rows 0..15 (T>=128 -> unmasked) ----
#pragma unroll
  for (int k = 1; k < 8; ++k) CTC_STEP(k, k, false, 0);
  CTC_STEP(8, 8, false, 1);
#pragma unroll
  for (int k = 9; k < 16; ++k) CTC_STEP(k, k, false, 0);
  CTC_BURST(0);

  // ---- main: unmasked fast path (t0+15 <= T-41) ----
  int t0 = 16;
  for (; t0 + 56 <= T; t0 += 16) {
    CTC_UNPACK(t0);
#pragma unroll
    for (int k = 0; k < 8; ++k) CTC_STEP(t0 + k, k, false, 0);
    CTC_STEP(t0 + 8, 8, false, 1);
#pragma unroll
    for (int k = 9; k < 16; ++k) CTC_STEP(t0 + k, k, false, 0);
    CTC_BURST(t0);
  }
  // ---- tail: masked blocks ----
  for (; t0 < T; t0 += 16) {
    CTC_UNPACK(t0);
#pragma unroll
    for (int k = 0; k < 8; ++k) CTC_STEP(t0 + k, k, true, 0);
    CTC_STEP(t0 + 8, 8, true, 1);
#pragma unroll
    for (int k = 9; k < 16; ++k) CTC_STEP(t0 + k, k, true, 0);
    CTC_BURST(t0);
  }
#undef CTC_STEP
#undef CTC_BURST
#undef CTC_UNPACK
#undef WS_LEVEL
}

// Fully parallel combine: block = item, thread = t. With the [b][t][pair]
// layout each thread's two rows are CONTIGUOUS 41-dword runs; adjacent
// threads read adjacent rows -> wave-level streams coalesce. lh_t =
// sum_p x'[t][p] * b'[T-1-t][p]; rows pre-normalized at store.
__global__ __launch_bounds__(256) void combine_kernel(
    const int* __restrict__ gw, const unsigned* __restrict__ xa,
    const unsigned* __restrict__ xb, float* __restrict__ loss_out) {
  const int b = blockIdx.x;
  const int tid = threadIdx.x;
  const int T = gw[b] >> 2;
  float lsum = 0.f;
  if (tid < T) {
    const unsigned* A = xa + ((size_t)b * MT + tid) * PAIRS;
    const unsigned* Bb = xb + ((size_t)b * MT + (T - 1 - tid)) * PAIRS;
    float d = 0.f;
#pragma unroll
    for (int p = 0; p < PAIRS; ++p) {
      const unsigned av = A[p];
      const unsigned bv = Bb[p];
      d = fmaf(bf_lo(av), bf_lo(bv), d);
      d = fmaf(bf_hi(av), bf_hi(bv), d);
    }
    lsum = -__logf(fmaxf(d, 1e-37f));
  }
  lsum = wave_sum(lsum);
  __shared__ float part[4];
  if ((tid & 63) == 0) part[tid >> 6] = lsum;
  __syncthreads();
  if (tid == 0) {
    float L = part[0] + part[1] + part[2] + part[3];
    loss_out[b] = fminf(fmaxf(L, -1e30f), 1e30f);  // fmin/fmax absorb NaN
  }
}

__global__ void reduce_kernel(const float* __restrict__ loss_in,
                              float* __restrict__ out) {
  __shared__ double sm[256];
  const int tid = threadIdx.x;
  double s = 0.0;
  for (int k = tid; k < BN; k += 256) s += (double)loss_in[k];
  sm[tid] = s;
  __syncthreads();
  for (int w = 128; w >= 1; w >>= 1) {
    if (tid < w) sm[tid] += sm[tid + w];
    __syncthreads();
  }
  if (tid == 0) out[0] = (float)sm[0];
}
}  // namespace

extern "C" void kernel_launch(void* const* d_in, const int* in_sizes, int n_in,
                              void* d_out, int out_size, void* d_ws, size_t ws_size,
                              hipStream_t stream) {
  const float* gout = (const float*)d_in[0];
  const int* glabel = (const int*)d_in[1];
  const int* gw = (const int*)d_in[2];
  unsigned* xa = (unsigned*)d_ws;                  // BN*MT*PAIRS uints (43 MB)
  unsigned* xb = xa + (size_t)BN * MT * PAIRS;     // 43 MB
  float* loss = (float*)(xb + (size_t)BN * MT * PAIRS);  // 4 KB
  chain_kernel<<<2 * BN, 64, 0, stream>>>(gout, glabel, gw, xa, xb);
  combine_kernel<<<BN, 256, 0, stream>>>(gw, xa, xb, loss);
  reduce_kernel<<<1, 256, 0, stream>>>(loss, (float*)d_out);
}